// Round 12
// baseline (1181.806 us; speedup 1.0000x reference)
//
#include <hip/hip_runtime.h>
#include <math.h>

#define H 2048
#define DIN 784
#define DPAD 896   // DIN padded to multiple of 128

typedef unsigned short ushort_t;
typedef __attribute__((ext_vector_type(8))) short bf16x8;
typedef __attribute__((ext_vector_type(4))) float f32x4;
typedef __attribute__((ext_vector_type(4))) unsigned short u16x4;
union F4 { float4 v; float a[4]; };
union U4 { u16x4 v; ushort_t a[4]; };

// ---------- helpers ----------
__device__ __forceinline__ float spu_f(float x){
    if (x >= 0.0f) return x*x - 0.5f;
    float s = 1.0f / (1.0f + __expf(x));   // sigmoid(-x)
    return s - 1.0f;
}
__device__ __forceinline__ float dspu_f(float x){
    if (x >= 0.0f) return 2.0f*x;
    float s = 1.0f / (1.0f + __expf(x));
    return -s * (1.0f - s);
}
__device__ __forceinline__ ushort_t f2bf(float x){
    unsigned u = __float_as_uint(x);
    unsigned r = (u + 0x7FFFu + ((u >> 16) & 1u)) >> 16;
    return (ushort_t)r;
}
__device__ __forceinline__ float bf2f(ushort_t h){
    return __uint_as_float((unsigned)h << 16);
}
__device__ __forceinline__ void load_lds16(const void* g, void* l){
    __builtin_amdgcn_global_load_lds((const __attribute__((address_space(1))) void*)g,
                                     (__attribute__((address_space(3))) void*)l,
                                     16, 0, 0);
}
__device__ __forceinline__ float block_reduce_256(float v, float* red){
    #pragma unroll
    for (int off = 32; off > 0; off >>= 1) v += __shfl_down(v, off, 64);
    int lane = threadIdx.x & 63, w = threadIdx.x >> 6;
    if (lane == 0) red[w] = v;
    __syncthreads();
    float t = 0.f;
    if (threadIdx.x == 0) t = red[0] + red[1] + red[2] + red[3];
    return t;   // valid on thread 0 only
}
__device__ __forceinline__ void block_reduce2_256(float vl, float vu, float* red,
                                                  float& out_l, float& out_u){
    #pragma unroll
    for (int off = 32; off > 0; off >>= 1){
        vl += __shfl_down(vl, off, 64);
        vu += __shfl_down(vu, off, 64);
    }
    int lane = threadIdx.x & 63, w = threadIdx.x >> 6;
    if (lane == 0){ red[w] = vl; red[4 + w] = vu; }
    __syncthreads();
    if (threadIdx.x == 0){
        out_l = red[0] + red[1] + red[2] + red[3];
        out_u = red[4] + red[5] + red[6] + red[7];
    }
}
__device__ __forceinline__ void spu_relax(float l, float u, float pl, float pu,
                                          float& wl_o, float& wu_o, float& bl_o, float& bu_o){
    float k1 = dspu_f(l), k2 = dspu_f(u);
    float klo = fminf(k1, k2), khi = fmaxf(k1, k2);
    float cwl = fminf(fmaxf(pl, klo), khi);
    float cwu = fminf(fmaxf(pu, klo), khi);
    float pts[4];
    pts[0] = l; pts[1] = u; pts[2] = 0.5f*(l+u); pts[3] = fminf(fmaxf(0.f, l), u);
    float bmin = INFINITY, bmax = -INFINITY;
    #pragma unroll
    for (int t = 0; t < 4; t++){
        float sp = spu_f(pts[t]);
        bmin = fminf(bmin, sp - cwl * pts[t]);
        bmax = fmaxf(bmax, sp - cwu * pts[t]);
    }
    wl_o = cwl; wu_o = cwu; bl_o = bmin; bu_o = bmax;
}

// ---------- merged: weight conversion (z=0,1) + stage-1 bounds (z=2) ----------
__global__ __launch_bounds__(256) void conv_bounds1(
    const float* __restrict__ W2, ushort_t* __restrict__ T2,
    const float* __restrict__ W1, ushort_t* __restrict__ T1,
    const float* __restrict__ b1,
    const float* __restrict__ l_in, const float* __restrict__ u_in,
    const float* __restrict__ pl, const float* __restrict__ pu,
    float* __restrict__ wl, float* __restrict__ wu,
    float* __restrict__ bl, float* __restrict__ bu)
{
    int z = blockIdx.z;
    if (z < 2){
        __shared__ float tile[32][33];
        const float* W = z ? W1 : W2;
        ushort_t* T = z ? T1 : T2;
        int K = H, N = z ? DIN : H, Npad = z ? DPAD : H;
        if (blockIdx.x * 32 >= (unsigned)Npad) return;
        int n0 = blockIdx.x * 32, k0 = blockIdx.y * 32;
        int tx = threadIdx.x & 31;
        int ty = threadIdx.x >> 5;   // 0..7
        #pragma unroll
        for (int i = 0; i < 32; i += 8){
            int k = k0 + ty + i, n = n0 + tx;
            tile[ty + i][tx] = (k < K && n < N) ? W[(size_t)k * N + n] : 0.f;
        }
        __syncthreads();
        #pragma unroll
        for (int i = 0; i < 32; i += 8){
            int n = n0 + ty + i, k = k0 + tx;
            if (n < Npad && k < K) T[(size_t)n * K + k] = f2bf(tile[tx][ty + i]);
        }
        return;
    }
    // z == 2: stage-1 bounds, row = blockIdx.y*64 + blockIdx.x
    int row = blockIdx.y * 64 + blockIdx.x;
    if (row >= H) return;
    __shared__ float red[8];
    const F4* Mr = (const F4*)(W1 + (size_t)row * DIN);
    const F4* li4 = (const F4*)l_in;
    const F4* ui4 = (const F4*)u_in;
    float accl = 0.f, accu = 0.f;
    for (int q = threadIdx.x; q < DIN/4; q += 256){
        F4 v = Mr[q], lo = li4[q], up = ui4[q];
        #pragma unroll
        for (int c = 0; c < 4; c++){
            float p = fmaxf(v.a[c], 0.f), n = fminf(v.a[c], 0.f);
            accl += p * lo.a[c] + n * up.a[c];
            accu += p * up.a[c] + n * lo.a[c];
        }
    }
    float tl, tu;
    block_reduce2_256(accl, accu, red, tl, tu);
    if (threadIdx.x == 0){
        float bb = b1[row];
        spu_relax(tl + bb, tu + bb, pl[row], pu[row],
                  wl[row], wu[row], bl[row], bu[row]);
    }
}

// ---------- dapply: stage-start dual (S shared by l and u, fp32, vectorized) ----------
__global__ __launch_bounds__(256) void dapply_dual(
    const float* __restrict__ S, const float* __restrict__ c_in,
    const float* __restrict__ wl, const float* __restrict__ wu,
    const float* __restrict__ bl, const float* __restrict__ bu,
    const float* __restrict__ bias_next,
    ushort_t* __restrict__ Ml, ushort_t* __restrict__ Mu,
    float* __restrict__ cl_out, float* __restrict__ cu_out, int ncols)
{
    __shared__ float red[8];
    int row = blockIdx.x;
    const F4* S4 = (const F4*)(S + (size_t)row * ncols);
    u16x4* Ml4 = (u16x4*)(Ml + (size_t)row * ncols);
    u16x4* Mu4 = (u16x4*)(Mu + (size_t)row * ncols);
    const F4* wl4 = (const F4*)wl; const F4* wu4 = (const F4*)wu;
    const F4* bl4 = (const F4*)bl; const F4* bu4 = (const F4*)bu;
    const F4* bn4 = (const F4*)bias_next;
    float accl = 0.f, accu = 0.f;
    for (int q = threadIdx.x; q < ncols/4; q += 256){
        F4 v = S4[q], a = wl4[q], b = wu4[q], c = bl4[q], d = bu4[q], e = bn4[q];
        U4 rl, ru;
        #pragma unroll
        for (int k = 0; k < 4; k++){
            float p = fmaxf(v.a[k], 0.f), n = fminf(v.a[k], 0.f);
            float ml = p * a.a[k] + n * b.a[k];
            float mu = p * b.a[k] + n * a.a[k];
            rl.a[k] = f2bf(ml);
            ru.a[k] = f2bf(mu);
            accl += p * c.a[k] + n * d.a[k] + ml * e.a[k];
            accu += p * d.a[k] + n * c.a[k] + mu * e.a[k];
        }
        Ml4[q] = rl.v;
        Mu4[q] = ru.v;
    }
    float tl, tu;
    block_reduce2_256(accl, accu, red, tl, tu);
    if (threadIdx.x == 0){
        float cc = c_in[row];
        cl_out[row] = cc + tl;
        cu_out[row] = cc + tu;
    }
}

// final output: out[row] = c[row] + sum_j mix(M[row][j]; pos_b,neg_b)
__global__ __launch_bounds__(256) void input_reduce(
    const float* __restrict__ M, const float* __restrict__ c,
    const float* __restrict__ pos_b, const float* __restrict__ neg_b,
    float* __restrict__ out, int ncols, int ld)
{
    __shared__ float red[4];
    int row = blockIdx.x;
    const float* Mr = M + (size_t)row * ld;
    float acc = 0.f;
    for (int j = threadIdx.x; j < ncols; j += 256){
        float v = Mr[j];
        acc += fmaxf(v, 0.f) * pos_b[j] + fminf(v, 0.f) * neg_b[j];
    }
    float t = block_reduce_256(acc, red);
    if (threadIdx.x == 0) out[row] = t + c[row];
}

// ---------- NN GEMM pair with FUSED dapply epilogue (full-K) ----------
#define TM 128
#define TN 128
#define TK 64
__global__ __launch_bounds__(512, 4) void gemm_nn_fused(
    const ushort_t* __restrict__ A_l, const ushort_t* __restrict__ A_u,
    const ushort_t* __restrict__ BT,
    ushort_t* __restrict__ O_l, ushort_t* __restrict__ O_u,
    const float* __restrict__ wl1, const float* __restrict__ wu1,
    const float* __restrict__ bl1, const float* __restrict__ bu1,
    const float* __restrict__ b1,
    float* __restrict__ cacc_l, float* __restrict__ cacc_u,
    int M, int N, int K)
{
    __shared__ ushort_t As[TM * TK];
    __shared__ ushort_t Bs[TN * TK];
    int lu = blockIdx.z;
    const ushort_t* A = lu ? A_u : A_l;
    ushort_t* O = lu ? O_u : O_l;
    float* cacc = lu ? cacc_u : cacc_l;
    const float* wp_a = lu ? wu1 : wl1;
    const float* wn_a = lu ? wl1 : wu1;
    const float* bp_a = lu ? bu1 : bl1;
    const float* bn_a = lu ? bl1 : bu1;

    int tid  = threadIdx.x;
    int wave = tid >> 6, lane = tid & 63;
    int wm = (wave >> 2) * 64, wn = (wave & 3) * 32;
    int l16 = lane & 15, quad = lane >> 4;
    int row0 = blockIdx.y * TM, col0 = blockIdx.x * TN;

    int r_lo = tid >> 3;
    int kp = (((tid & 7) ^ (r_lo & 7)) * 8);
    const ushort_t *aSrc[2], *bSrc[2];
    ushort_t *aDst[2], *bDst[2];
    #pragma unroll
    for (int g = 0; g < 2; g++){
        aSrc[g] = A  + (size_t)(row0 + g*64 + r_lo) * K + kp;
        bSrc[g] = BT + (size_t)(col0 + g*64 + r_lo) * K + kp;
        aDst[g] = As + g*4096 + wave*512;
        bDst[g] = Bs + g*4096 + wave*512;
    }

    f32x4 acc[4][2];
    #pragma unroll
    for (int i = 0; i < 4; i++)
        #pragma unroll
        for (int j = 0; j < 2; j++)
            acc[i][j] = (f32x4){0.f, 0.f, 0.f, 0.f};

    for (int kk0 = 0; kk0 < K; kk0 += TK){
        #pragma unroll
        for (int g = 0; g < 2; g++) load_lds16(aSrc[g], aDst[g]);
        #pragma unroll
        for (int g = 0; g < 2; g++) load_lds16(bSrc[g], bDst[g]);
        #pragma unroll
        for (int g = 0; g < 2; g++){ aSrc[g] += TK; bSrc[g] += TK; }
        __syncthreads();

        #pragma unroll
        for (int half = 0; half < 2; half++){
            bf16x8 af[4], bf[2];
            #pragma unroll
            for (int t = 0; t < 4; t++){
                int ra = wm + t*16 + l16;
                int sa = (half*4 + quad) ^ (ra & 7);
                af[t] = *(const bf16x8*)&As[ra * TK + sa * 8];
            }
            #pragma unroll
            for (int t = 0; t < 2; t++){
                int rb = wn + t*16 + l16;
                int sb = (half*4 + quad) ^ (rb & 7);
                bf[t] = *(const bf16x8*)&Bs[rb * TK + sb * 8];
            }
            #pragma unroll
            for (int i = 0; i < 4; i++)
                #pragma unroll
                for (int j = 0; j < 2; j++)
                    acc[i][j] = __builtin_amdgcn_mfma_f32_16x16x32_bf16(af[i], bf[j], acc[i][j], 0, 0, 0);
        }
        __syncthreads();
    }

    // fused dapply epilogue (C/D layout: col = lane&15, row = quad*4 + reg)
    int cc0 = col0 + wn + l16;
    int cc1 = cc0 + 16;
    float wp0 = wp_a[cc0], wn0 = wn_a[cc0], bp0 = bp_a[cc0], bn0 = bn_a[cc0], bb0 = b1[cc0];
    float wp1 = wp_a[cc1], wn1 = wn_a[cc1], bp1 = bp_a[cc1], bn1 = bn_a[cc1], bb1 = b1[cc1];
    #pragma unroll
    for (int i = 0; i < 4; i++){
        int rbase = row0 + wm + i*16 + quad*4;
        #pragma unroll
        for (int rr = 0; rr < 4; rr++){
            int r = rbase + rr;
            float v0 = acc[i][0][rr];
            float p0 = fmaxf(v0, 0.f), n0 = fminf(v0, 0.f);
            float m0 = p0 * wp0 + n0 * wn0;
            O[(size_t)r * N + cc0] = f2bf(m0);
            float s = p0 * bp0 + n0 * bn0 + m0 * bb0;
            float v1 = acc[i][1][rr];
            float p1 = fmaxf(v1, 0.f), n1 = fminf(v1, 0.f);
            float m1 = p1 * wp1 + n1 * wn1;
            O[(size_t)r * N + cc1] = f2bf(m1);
            s += p1 * bp1 + n1 * bn1 + m1 * bb1;
            s += __shfl_down(s, 8, 16);
            s += __shfl_down(s, 4, 16);
            s += __shfl_down(s, 2, 16);
            s += __shfl_down(s, 1, 16);
            if (l16 == 0) atomicAdd(&cacc[r], s);
        }
    }
}

// ---------- ND GEMM pair, 64x64 tile, fused bounds-mix + LAST-DONE SPU relax ----------
// 256 threads, 4 waves of 32x32. Full-K. Per-row contributions: 14 x-blocks x
// 2 wn-waves x 2 lu = 56. The 56th contributor performs the SPU relaxation.
#define TN2 64
__global__ __launch_bounds__(256, 4) void gemm_nd_fused(
    const ushort_t* __restrict__ A_l, const ushort_t* __restrict__ A_u,
    const ushort_t* __restrict__ BT,
    const float* __restrict__ l_in, const float* __restrict__ u_in,
    float* __restrict__ acc_l, float* __restrict__ acc_u,
    unsigned* __restrict__ cnt,
    const float* __restrict__ c1l, const float* __restrict__ c1u,
    const float* __restrict__ c2l, const float* __restrict__ c2u,
    const float* __restrict__ pl, const float* __restrict__ pu,
    float* __restrict__ wl_o, float* __restrict__ wu_o,
    float* __restrict__ bl_o, float* __restrict__ bu_o,
    int M, int N, int K, unsigned target)
{
    __shared__ ushort_t As[64 * TK];   // 8 KB
    __shared__ ushort_t Bs[64 * TK];   // 8 KB
    int lu = blockIdx.z;
    const ushort_t* A = lu ? A_u : A_l;
    float* accv = lu ? acc_u : acc_l;

    int tid  = threadIdx.x;
    int wave = tid >> 6, lane = tid & 63;
    int wm = (wave >> 1) * 32, wn = (wave & 1) * 32;
    int l16 = lane & 15, quad = lane >> 4;
    int row0 = blockIdx.y * 64, col0 = blockIdx.x * TN2;

    int r_lo = tid >> 3;                       // 0..31
    int kp = (((tid & 7) ^ (r_lo & 7)) * 8);
    const ushort_t *aSrc[2], *bSrc[2];
    ushort_t *aDst[2], *bDst[2];
    #pragma unroll
    for (int g = 0; g < 2; g++){
        aSrc[g] = A  + (size_t)(row0 + g*32 + r_lo) * K + kp;
        bSrc[g] = BT + (size_t)(col0 + g*32 + r_lo) * K + kp;
        aDst[g] = As + g*2048 + wave*512;
        bDst[g] = Bs + g*2048 + wave*512;
    }

    f32x4 acc[2][2];
    #pragma unroll
    for (int i = 0; i < 2; i++)
        #pragma unroll
        for (int j = 0; j < 2; j++)
            acc[i][j] = (f32x4){0.f, 0.f, 0.f, 0.f};

    for (int kk0 = 0; kk0 < K; kk0 += TK){
        #pragma unroll
        for (int g = 0; g < 2; g++) load_lds16(aSrc[g], aDst[g]);
        #pragma unroll
        for (int g = 0; g < 2; g++) load_lds16(bSrc[g], bDst[g]);
        #pragma unroll
        for (int g = 0; g < 2; g++){ aSrc[g] += TK; bSrc[g] += TK; }
        __syncthreads();

        #pragma unroll
        for (int half = 0; half < 2; half++){
            bf16x8 af[2], bf[2];
            #pragma unroll
            for (int t = 0; t < 2; t++){
                int ra = wm + t*16 + l16;
                int sa = (half*4 + quad) ^ (ra & 7);
                af[t] = *(const bf16x8*)&As[ra * TK + sa * 8];
                int rb = wn + t*16 + l16;
                int sb = (half*4 + quad) ^ (rb & 7);
                bf[t] = *(const bf16x8*)&Bs[rb * TK + sb * 8];
            }
            #pragma unroll
            for (int i = 0; i < 2; i++)
                #pragma unroll
                for (int j = 0; j < 2; j++)
                    acc[i][j] = __builtin_amdgcn_mfma_f32_16x16x32_bf16(af[i], bf[j], acc[i][j], 0, 0, 0);
        }
        __syncthreads();
    }

    // fused bounds epilogue + last-done SPU relax
    int cc0 = col0 + wn + l16;
    int cc1 = cc0 + 16;
    float pb0 = 0.f, nb0 = 0.f, pb1 = 0.f, nb1 = 0.f;
    if (cc0 < DIN){ pb0 = lu ? u_in[cc0] : l_in[cc0]; nb0 = lu ? l_in[cc0] : u_in[cc0]; }
    if (cc1 < DIN){ pb1 = lu ? u_in[cc1] : l_in[cc1]; nb1 = lu ? l_in[cc1] : u_in[cc1]; }
    #pragma unroll
    for (int i = 0; i < 2; i++){
        int rbase = row0 + wm + i*16 + quad*4;
        #pragma unroll
        for (int rr = 0; rr < 4; rr++){
            int r = rbase + rr;
            float v0 = acc[i][0][rr];
            float s = fmaxf(v0, 0.f) * pb0 + fminf(v0, 0.f) * nb0;
            float v1 = acc[i][1][rr];
            s += fmaxf(v1, 0.f) * pb1 + fminf(v1, 0.f) * nb1;
            s += __shfl_down(s, 8, 16);
            s += __shfl_down(s, 4, 16);
            s += __shfl_down(s, 2, 16);
            s += __shfl_down(s, 1, 16);
            if (l16 == 0){
                atomicAdd(&accv[r], s);
                __threadfence();
                unsigned old = atomicAdd(&cnt[r], 1u);
                if (old == target - 1){
                    __threadfence();
                    // read through the L2-atomic path (device-coherent)
                    float lsum = atomicAdd(&acc_l[r], 0.f);
                    float usum = atomicAdd(&acc_u[r], 0.f);
                    float lb = lsum + c1l[r] + (c2l ? c2l[r] : 0.f);
                    float ub = usum + c1u[r] + (c2u ? c2u[r] : 0.f);
                    spu_relax(lb, ub, pl[r], pu[r],
                              wl_o[r], wu_o[r], bl_o[r], bu_o[r]);
                }
            }
        }
    }
}

// ---------- fused final-chain GEMV (9 rows), 64-thr blocks, 64 cols x 32-k slices ----------
#define GCOLS 64
#define GKS 32
__global__ __launch_bounds__(64) void gemv9_fused(
    const float* __restrict__ S,
    const float* __restrict__ W4, const float* __restrict__ b4,
    const int* __restrict__ tlp, int mode_w4,
    const float* __restrict__ c_in,
    const float* __restrict__ w_pos, const float* __restrict__ w_neg,
    const float* __restrict__ b_pos, const float* __restrict__ b_neg,
    const float* __restrict__ bias_next,
    const float* __restrict__ B, int K, int N,
    float* __restrict__ C, float* __restrict__ c_out)
{
    __shared__ float Alds[9][GKS];
    int j = threadIdx.x;          // 0..63
    int k0 = blockIdx.y * GKS;
    int tl = mode_w4 ? *tlp : 0;
    float pc[9];
    #pragma unroll
    for (int r = 0; r < 9; r++) pc[r] = 0.f;
    if (j < GKS){
        int k = k0 + j;
        float wp = w_pos[k], wn = w_neg[k], bp = b_pos[k], bn = b_neg[k], bb = bias_next[k];
        #pragma unroll
        for (int r = 0; r < 9; r++){
            float v;
            if (mode_w4){
                int kr = r + (r >= tl ? 1 : 0);
                v = W4[(size_t)kr * K + k] - W4[(size_t)tl * K + k];
            } else {
                v = S[(size_t)r * K + k];
            }
            float p = fmaxf(v, 0.f), n = fminf(v, 0.f);
            float m = p * wp + n * wn;
            Alds[r][j] = m;
            pc[r] = p * bp + n * bn + m * bb;
        }
    }
    if (blockIdx.x == 0){
        #pragma unroll
        for (int r = 0; r < 9; r++){
            float v = pc[r];
            #pragma unroll
            for (int o = 32; o > 0; o >>= 1) v += __shfl_down(v, o, 64);
            if (j == 0){
                if (blockIdx.y == 0)
                    v += mode_w4 ? (b4[r + (r >= tl ? 1 : 0)] - b4[tl]) : c_in[r];
                atomicAdd(&c_out[r], v);
            }
        }
    }
    __syncthreads();
    int col = blockIdx.x * GCOLS + j;
    if (col < N){
        float acc[9] = {0.f,0.f,0.f,0.f,0.f,0.f,0.f,0.f,0.f};
        for (int kk = 0; kk < GKS; kk++){
            float b = B[(size_t)(k0 + kk) * N + col];
            #pragma unroll
            for (int r = 0; r < 9; r++) acc[r] += Alds[r][kk] * b;
        }
        #pragma unroll
        for (int r = 0; r < 9; r++) atomicAdd(&C[(size_t)r * N + col], acc[r]);
    }
}

extern "C" void kernel_launch(void* const* d_in, const int* in_sizes, int n_in,
                              void* d_out, int out_size, void* d_ws, size_t ws_size,
                              hipStream_t stream)
{
    const float* W1  = (const float*)d_in[0];
    const float* b1  = (const float*)d_in[1];
    const float* W2  = (const float*)d_in[2];
    const float* b2  = (const float*)d_in[3];
    const float* W3  = (const float*)d_in[4];
    const float* b3  = (const float*)d_in[5];
    const float* W4  = (const float*)d_in[6];
    const float* b4  = (const float*)d_in[7];
    const float* l_in = (const float*)d_in[8];
    const float* u_in = (const float*)d_in[9];
    const float* p_l1 = (const float*)d_in[10];
    const float* p_u1 = (const float*)d_in[11];
    const float* p_l2 = (const float*)d_in[12];
    const float* p_u2 = (const float*)d_in[13];
    const float* p_l3 = (const float*)d_in[14];
    const float* p_u3 = (const float*)d_in[15];
    const int*   tl   = (const int*)d_in[16];
    float* out = (float*)d_out;

    size_t off = 0;
    auto allocB = [&](size_t bytes) -> void* {
        void* p = (char*)d_ws + off;
        off += (bytes + 255) & ~(size_t)255;
        return p;
    };
    ushort_t* W1bt  = (ushort_t*)allocB((size_t)DPAD * H * 2);
    ushort_t* W2bt  = (ushort_t*)allocB((size_t)H * H * 2);
    ushort_t* Abf_l = (ushort_t*)allocB((size_t)H * H * 2);   // dapply outputs
    ushort_t* Abf_u = (ushort_t*)allocB((size_t)H * H * 2);
    ushort_t* P_l = (ushort_t*)allocB((size_t)H * H * 2);     // NN fused outputs
    ushort_t* P_u = (ushort_t*)allocB((size_t)H * H * 2);
    float *wl1=(float*)allocB(H*4), *wu1=(float*)allocB(H*4), *bl1=(float*)allocB(H*4), *bu1=(float*)allocB(H*4);
    float *wl2=(float*)allocB(H*4), *wu2=(float*)allocB(H*4), *bl2=(float*)allocB(H*4), *bu2=(float*)allocB(H*4);
    float *wl3=(float*)allocB(H*4), *wu3=(float*)allocB(H*4), *bl3=(float*)allocB(H*4), *bu3=(float*)allocB(H*4);
    float *cl_a=(float*)allocB(H*4), *cu_a=(float*)allocB(H*4);
    // ---- zeroed region (one memset): accumulators + counters + final chain ----
    size_t zero_begin = off;
    float *la2=(float*)allocB(H*4), *ua2=(float*)allocB(H*4);
    float *la3=(float*)allocB(H*4), *ua3=(float*)allocB(H*4);
    float *cl_b=(float*)allocB(H*4), *cu_b=(float*)allocB(H*4);
    unsigned *cnt2=(unsigned*)allocB(H*4), *cnt3=(unsigned*)allocB(H*4);
    float* F1  = (float*)allocB(9 * H * 4);
    float* F2  = (float*)allocB(9 * H * 4);
    float* F3  = (float*)allocB(9 * DIN * 4);
    float *c9b=(float*)allocB(64), *c9c=(float*)allocB(64), *c9d=(float*)allocB(64);
    size_t zero_bytes = off - zero_begin;

    dim3 blk(256);
    dim3 gblk(512);
    dim3 gND(DPAD/TN2, H/64, 2);   // 14 x 32 x 2 = 896 blocks
    const unsigned ND_TARGET = (DPAD/TN2) * 2 * 2;   // x-blocks * wn-waves * lu = 56

    // 1. zero accumulators + counters (single memset)
    hipMemsetAsync((char*)d_ws + zero_begin, 0, zero_bytes, stream);

    // 2. weight conversion + stage-1 bounds (merged)
    conv_bounds1<<<dim3(H/32, H/32, 3), blk, 0, stream>>>(
        W2, W2bt, W1, W1bt, b1, l_in, u_in, p_l1, p_u1, wl1, wu1, bl1, bu1);

    // 3-4. stage 2: (W2,b2) -> D1 -> [@W1 + fused bounds-mix + in-kernel relax]
    dapply_dual<<<H, blk, 0, stream>>>(W2, b2, wl1, wu1, bl1, bu1, b1,
                                       Abf_l, Abf_u, cl_a, cu_a, H);
    gemm_nd_fused<<<gND, blk, 0, stream>>>(Abf_l, Abf_u, W1bt, l_in, u_in,
                                           la2, ua2, cnt2, cl_a, cu_a, nullptr, nullptr,
                                           p_l2, p_u2, wl2, wu2, bl2, bu2,
                                           H, DPAD, H, ND_TARGET);

    // 5-7. stage 3: (W3,b3) -> D2 -> [@W2 + fused D1] -> [@W1 + fused relax]
    dapply_dual<<<H, blk, 0, stream>>>(W3, b3, wl2, wu2, bl2, bu2, b2,
                                       Abf_l, Abf_u, cl_a, cu_a, H);
    gemm_nn_fused<<<dim3(H/TN, H/TM, 2), gblk, 0, stream>>>(
        Abf_l, Abf_u, W2bt, P_l, P_u,
        wl1, wu1, bl1, bu1, b1, cl_b, cu_b, H, H, H);
    gemm_nd_fused<<<gND, blk, 0, stream>>>(P_l, P_u, W1bt, l_in, u_in,
                                           la3, ua3, cnt3, cl_b, cu_b, cl_a, cu_a,
                                           p_l3, p_u3, wl3, wu3, bl3, bu3,
                                           H, DPAD, H, ND_TARGET);

    // 8-11. final chain (upper bound only), 9 rows
    gemv9_fused<<<dim3(H/GCOLS, H/GKS), dim3(64), 0, stream>>>(
        nullptr, W4, b4, tl, 1, nullptr,
        wu3, wl3, bu3, bl3, b3, W3, H, H, F1, c9b);
    gemv9_fused<<<dim3(H/GCOLS, H/GKS), dim3(64), 0, stream>>>(
        F1, nullptr, nullptr, nullptr, 0, c9b,
        wu2, wl2, bu2, bl2, b2, W2, H, H, F2, c9c);
    gemv9_fused<<<dim3((DIN + GCOLS - 1)/GCOLS, H/GKS), dim3(64), 0, stream>>>(
        F2, nullptr, nullptr, nullptr, 0, c9c,
        wu1, wl1, bu1, bl1, b1, W1, H, DIN, F3, c9d);
    input_reduce<<<9, blk, 0, stream>>>(F3, c9d, u_in, l_in, out, DIN, DIN);
}

// Round 13
// 313.130 us; speedup vs baseline: 3.7742x; 3.7742x over previous
//
#include <hip/hip_runtime.h>
#include <math.h>

#define H 2048
#define DIN 784
#define DPAD 896   // DIN padded to multiple of 128

typedef unsigned short ushort_t;
typedef __attribute__((ext_vector_type(8))) short bf16x8;
typedef __attribute__((ext_vector_type(4))) float f32x4;
typedef __attribute__((ext_vector_type(4))) unsigned short u16x4;
union F4 { float4 v; float a[4]; };
union U4 { u16x4 v; ushort_t a[4]; };

// ---------- helpers ----------
__device__ __forceinline__ float spu_f(float x){
    if (x >= 0.0f) return x*x - 0.5f;
    float s = 1.0f / (1.0f + __expf(x));   // sigmoid(-x)
    return s - 1.0f;
}
__device__ __forceinline__ float dspu_f(float x){
    if (x >= 0.0f) return 2.0f*x;
    float s = 1.0f / (1.0f + __expf(x));
    return -s * (1.0f - s);
}
__device__ __forceinline__ ushort_t f2bf(float x){
    unsigned u = __float_as_uint(x);
    unsigned r = (u + 0x7FFFu + ((u >> 16) & 1u)) >> 16;
    return (ushort_t)r;
}
__device__ __forceinline__ float bf2f(ushort_t h){
    return __uint_as_float((unsigned)h << 16);
}
__device__ __forceinline__ void load_lds16(const void* g, void* l){
    __builtin_amdgcn_global_load_lds((const __attribute__((address_space(1))) void*)g,
                                     (__attribute__((address_space(3))) void*)l,
                                     16, 0, 0);
}
__device__ __forceinline__ float block_reduce_256(float v, float* red){
    #pragma unroll
    for (int off = 32; off > 0; off >>= 1) v += __shfl_down(v, off, 64);
    int lane = threadIdx.x & 63, w = threadIdx.x >> 6;
    if (lane == 0) red[w] = v;
    __syncthreads();
    float t = 0.f;
    if (threadIdx.x == 0) t = red[0] + red[1] + red[2] + red[3];
    return t;   // valid on thread 0 only
}
__device__ __forceinline__ void block_reduce2_256(float vl, float vu, float* red,
                                                  float& out_l, float& out_u){
    #pragma unroll
    for (int off = 32; off > 0; off >>= 1){
        vl += __shfl_down(vl, off, 64);
        vu += __shfl_down(vu, off, 64);
    }
    int lane = threadIdx.x & 63, w = threadIdx.x >> 6;
    if (lane == 0){ red[w] = vl; red[4 + w] = vu; }
    __syncthreads();
    if (threadIdx.x == 0){
        out_l = red[0] + red[1] + red[2] + red[3];
        out_u = red[4] + red[5] + red[6] + red[7];
    }
}
__device__ __forceinline__ void spu_relax(float l, float u, float pl, float pu,
                                          float& wl_o, float& wu_o, float& bl_o, float& bu_o){
    float k1 = dspu_f(l), k2 = dspu_f(u);
    float klo = fminf(k1, k2), khi = fmaxf(k1, k2);
    float cwl = fminf(fmaxf(pl, klo), khi);
    float cwu = fminf(fmaxf(pu, klo), khi);
    float pts[4];
    pts[0] = l; pts[1] = u; pts[2] = 0.5f*(l+u); pts[3] = fminf(fmaxf(0.f, l), u);
    float bmin = INFINITY, bmax = -INFINITY;
    #pragma unroll
    for (int t = 0; t < 4; t++){
        float sp = spu_f(pts[t]);
        bmin = fminf(bmin, sp - cwl * pts[t]);
        bmax = fmaxf(bmax, sp - cwu * pts[t]);
    }
    wl_o = cwl; wu_o = cwu; bl_o = bmin; bu_o = bmax;
}

// ---------- merged: weight conversion (z=0,1) + stage-1 bounds (z=2) ----------
__global__ __launch_bounds__(256) void conv_bounds1(
    const float* __restrict__ W2, ushort_t* __restrict__ T2,
    const float* __restrict__ W1, ushort_t* __restrict__ T1,
    const float* __restrict__ b1,
    const float* __restrict__ l_in, const float* __restrict__ u_in,
    const float* __restrict__ pl, const float* __restrict__ pu,
    float* __restrict__ wl, float* __restrict__ wu,
    float* __restrict__ bl, float* __restrict__ bu)
{
    int z = blockIdx.z;
    if (z < 2){
        __shared__ float tile[32][33];
        const float* W = z ? W1 : W2;
        ushort_t* T = z ? T1 : T2;
        int K = H, N = z ? DIN : H, Npad = z ? DPAD : H;
        if (blockIdx.x * 32 >= (unsigned)Npad) return;
        int n0 = blockIdx.x * 32, k0 = blockIdx.y * 32;
        int tx = threadIdx.x & 31;
        int ty = threadIdx.x >> 5;   // 0..7
        #pragma unroll
        for (int i = 0; i < 32; i += 8){
            int k = k0 + ty + i, n = n0 + tx;
            tile[ty + i][tx] = (k < K && n < N) ? W[(size_t)k * N + n] : 0.f;
        }
        __syncthreads();
        #pragma unroll
        for (int i = 0; i < 32; i += 8){
            int n = n0 + ty + i, k = k0 + tx;
            if (n < Npad && k < K) T[(size_t)n * K + k] = f2bf(tile[tx][ty + i]);
        }
        return;
    }
    // z == 2: stage-1 bounds, row = blockIdx.y*64 + blockIdx.x
    int row = blockIdx.y * 64 + blockIdx.x;
    if (row >= H) return;
    __shared__ float red[8];
    const F4* Mr = (const F4*)(W1 + (size_t)row * DIN);
    const F4* li4 = (const F4*)l_in;
    const F4* ui4 = (const F4*)u_in;
    float accl = 0.f, accu = 0.f;
    for (int q = threadIdx.x; q < DIN/4; q += 256){
        F4 v = Mr[q], lo = li4[q], up = ui4[q];
        #pragma unroll
        for (int c = 0; c < 4; c++){
            float p = fmaxf(v.a[c], 0.f), n = fminf(v.a[c], 0.f);
            accl += p * lo.a[c] + n * up.a[c];
            accu += p * up.a[c] + n * lo.a[c];
        }
    }
    float tl, tu;
    block_reduce2_256(accl, accu, red, tl, tu);
    if (threadIdx.x == 0){
        float bb = b1[row];
        spu_relax(tl + bb, tu + bb, pl[row], pu[row],
                  wl[row], wu[row], bl[row], bu[row]);
    }
}

// ---------- per-row SPU relaxation from fused ND accumulators ----------
__global__ __launch_bounds__(256) void spu_relax_rows(
    const float* __restrict__ accl, const float* __restrict__ accu,
    const float* __restrict__ c1l, const float* __restrict__ c1u,
    const float* __restrict__ c2l, const float* __restrict__ c2u,
    const float* __restrict__ pl, const float* __restrict__ pu,
    float* __restrict__ wl, float* __restrict__ wu,
    float* __restrict__ bl, float* __restrict__ bu, int n)
{
    int i = blockIdx.x * 256 + threadIdx.x;
    if (i >= n) return;
    float l = accl[i] + c1l[i] + (c2l ? c2l[i] : 0.f);
    float u = accu[i] + c1u[i] + (c2u ? c2u[i] : 0.f);
    spu_relax(l, u, pl[i], pu[i], wl[i], wu[i], bl[i], bu[i]);
}

// ---------- dapply: stage-start dual (S shared by l and u, fp32, vectorized) ----------
__global__ __launch_bounds__(256) void dapply_dual(
    const float* __restrict__ S, const float* __restrict__ c_in,
    const float* __restrict__ wl, const float* __restrict__ wu,
    const float* __restrict__ bl, const float* __restrict__ bu,
    const float* __restrict__ bias_next,
    ushort_t* __restrict__ Ml, ushort_t* __restrict__ Mu,
    float* __restrict__ cl_out, float* __restrict__ cu_out, int ncols)
{
    __shared__ float red[8];
    int row = blockIdx.x;
    const F4* S4 = (const F4*)(S + (size_t)row * ncols);
    u16x4* Ml4 = (u16x4*)(Ml + (size_t)row * ncols);
    u16x4* Mu4 = (u16x4*)(Mu + (size_t)row * ncols);
    const F4* wl4 = (const F4*)wl; const F4* wu4 = (const F4*)wu;
    const F4* bl4 = (const F4*)bl; const F4* bu4 = (const F4*)bu;
    const F4* bn4 = (const F4*)bias_next;
    float accl = 0.f, accu = 0.f;
    for (int q = threadIdx.x; q < ncols/4; q += 256){
        F4 v = S4[q], a = wl4[q], b = wu4[q], c = bl4[q], d = bu4[q], e = bn4[q];
        U4 rl, ru;
        #pragma unroll
        for (int k = 0; k < 4; k++){
            float p = fmaxf(v.a[k], 0.f), n = fminf(v.a[k], 0.f);
            float ml = p * a.a[k] + n * b.a[k];
            float mu = p * b.a[k] + n * a.a[k];
            rl.a[k] = f2bf(ml);
            ru.a[k] = f2bf(mu);
            accl += p * c.a[k] + n * d.a[k] + ml * e.a[k];
            accu += p * d.a[k] + n * c.a[k] + mu * e.a[k];
        }
        Ml4[q] = rl.v;
        Mu4[q] = ru.v;
    }
    float tl, tu;
    block_reduce2_256(accl, accu, red, tl, tu);
    if (threadIdx.x == 0){
        float cc = c_in[row];
        cl_out[row] = cc + tl;
        cu_out[row] = cc + tu;
    }
}

// final output: out[row] = c[row] + sum_j mix(M[row][j]; pos_b,neg_b)
__global__ __launch_bounds__(256) void input_reduce(
    const float* __restrict__ M, const float* __restrict__ c,
    const float* __restrict__ pos_b, const float* __restrict__ neg_b,
    float* __restrict__ out, int ncols, int ld)
{
    __shared__ float red[4];
    int row = blockIdx.x;
    const float* Mr = M + (size_t)row * ld;
    float acc = 0.f;
    for (int j = threadIdx.x; j < ncols; j += 256){
        float v = Mr[j];
        acc += fmaxf(v, 0.f) * pos_b[j] + fminf(v, 0.f) * neg_b[j];
    }
    float t = block_reduce_256(acc, red);
    if (threadIdx.x == 0) out[row] = t + c[row];
}

// ---------- NN GEMM pair with FUSED dapply epilogue (full-K) ----------
#define TM 128
#define TN 128
#define TK 64
__global__ __launch_bounds__(512, 4) void gemm_nn_fused(
    const ushort_t* __restrict__ A_l, const ushort_t* __restrict__ A_u,
    const ushort_t* __restrict__ BT,
    ushort_t* __restrict__ O_l, ushort_t* __restrict__ O_u,
    const float* __restrict__ wl1, const float* __restrict__ wu1,
    const float* __restrict__ bl1, const float* __restrict__ bu1,
    const float* __restrict__ b1,
    float* __restrict__ cacc_l, float* __restrict__ cacc_u,
    int M, int N, int K)
{
    __shared__ ushort_t As[TM * TK];
    __shared__ ushort_t Bs[TN * TK];
    int lu = blockIdx.z;
    const ushort_t* A = lu ? A_u : A_l;
    ushort_t* O = lu ? O_u : O_l;
    float* cacc = lu ? cacc_u : cacc_l;
    const float* wp_a = lu ? wu1 : wl1;
    const float* wn_a = lu ? wl1 : wu1;
    const float* bp_a = lu ? bu1 : bl1;
    const float* bn_a = lu ? bl1 : bu1;

    int tid  = threadIdx.x;
    int wave = tid >> 6, lane = tid & 63;
    int wm = (wave >> 2) * 64, wn = (wave & 3) * 32;
    int l16 = lane & 15, quad = lane >> 4;
    int row0 = blockIdx.y * TM, col0 = blockIdx.x * TN;

    int r_lo = tid >> 3;
    int kp = (((tid & 7) ^ (r_lo & 7)) * 8);
    const ushort_t *aSrc[2], *bSrc[2];
    ushort_t *aDst[2], *bDst[2];
    #pragma unroll
    for (int g = 0; g < 2; g++){
        aSrc[g] = A  + (size_t)(row0 + g*64 + r_lo) * K + kp;
        bSrc[g] = BT + (size_t)(col0 + g*64 + r_lo) * K + kp;
        aDst[g] = As + g*4096 + wave*512;
        bDst[g] = Bs + g*4096 + wave*512;
    }

    f32x4 acc[4][2];
    #pragma unroll
    for (int i = 0; i < 4; i++)
        #pragma unroll
        for (int j = 0; j < 2; j++)
            acc[i][j] = (f32x4){0.f, 0.f, 0.f, 0.f};

    for (int kk0 = 0; kk0 < K; kk0 += TK){
        #pragma unroll
        for (int g = 0; g < 2; g++) load_lds16(aSrc[g], aDst[g]);
        #pragma unroll
        for (int g = 0; g < 2; g++) load_lds16(bSrc[g], bDst[g]);
        #pragma unroll
        for (int g = 0; g < 2; g++){ aSrc[g] += TK; bSrc[g] += TK; }
        __syncthreads();

        #pragma unroll
        for (int half = 0; half < 2; half++){
            bf16x8 af[4], bf[2];
            #pragma unroll
            for (int t = 0; t < 4; t++){
                int ra = wm + t*16 + l16;
                int sa = (half*4 + quad) ^ (ra & 7);
                af[t] = *(const bf16x8*)&As[ra * TK + sa * 8];
            }
            #pragma unroll
            for (int t = 0; t < 2; t++){
                int rb = wn + t*16 + l16;
                int sb = (half*4 + quad) ^ (rb & 7);
                bf[t] = *(const bf16x8*)&Bs[rb * TK + sb * 8];
            }
            #pragma unroll
            for (int i = 0; i < 4; i++)
                #pragma unroll
                for (int j = 0; j < 2; j++)
                    acc[i][j] = __builtin_amdgcn_mfma_f32_16x16x32_bf16(af[i], bf[j], acc[i][j], 0, 0, 0);
        }
        __syncthreads();
    }

    // fused dapply epilogue (C/D layout: col = lane&15, row = quad*4 + reg)
    int cc0 = col0 + wn + l16;
    int cc1 = cc0 + 16;
    float wp0 = wp_a[cc0], wn0 = wn_a[cc0], bp0 = bp_a[cc0], bn0 = bn_a[cc0], bb0 = b1[cc0];
    float wp1 = wp_a[cc1], wn1 = wn_a[cc1], bp1 = bp_a[cc1], bn1 = bn_a[cc1], bb1 = b1[cc1];
    #pragma unroll
    for (int i = 0; i < 4; i++){
        int rbase = row0 + wm + i*16 + quad*4;
        #pragma unroll
        for (int rr = 0; rr < 4; rr++){
            int r = rbase + rr;
            float v0 = acc[i][0][rr];
            float p0 = fmaxf(v0, 0.f), n0 = fminf(v0, 0.f);
            float m0 = p0 * wp0 + n0 * wn0;
            O[(size_t)r * N + cc0] = f2bf(m0);
            float s = p0 * bp0 + n0 * bn0 + m0 * bb0;
            float v1 = acc[i][1][rr];
            float p1 = fmaxf(v1, 0.f), n1 = fminf(v1, 0.f);
            float m1 = p1 * wp1 + n1 * wn1;
            O[(size_t)r * N + cc1] = f2bf(m1);
            s += p1 * bp1 + n1 * bn1 + m1 * bb1;
            s += __shfl_down(s, 8, 16);
            s += __shfl_down(s, 4, 16);
            s += __shfl_down(s, 2, 16);
            s += __shfl_down(s, 1, 16);
            if (l16 == 0) atomicAdd(&cacc[r], s);
        }
    }
}

// ---------- ND GEMM pair, 64x64 tile, fused bounds-mix epilogue (plain atomics) ----------
// 256 threads, 4 waves of 32x32, full-K, 896 blocks (3.5/CU).
#define TN2 64
__global__ __launch_bounds__(256, 4) void gemm_nd_fused(
    const ushort_t* __restrict__ A_l, const ushort_t* __restrict__ A_u,
    const ushort_t* __restrict__ BT,
    const float* __restrict__ l_in, const float* __restrict__ u_in,
    float* __restrict__ acc_l, float* __restrict__ acc_u,
    int M, int N, int K)
{
    __shared__ ushort_t As[64 * TK];   // 8 KB
    __shared__ ushort_t Bs[64 * TK];   // 8 KB
    int lu = blockIdx.z;
    const ushort_t* A = lu ? A_u : A_l;
    float* accv = lu ? acc_u : acc_l;

    int tid  = threadIdx.x;
    int wave = tid >> 6, lane = tid & 63;
    int wm = (wave >> 1) * 32, wn = (wave & 1) * 32;
    int l16 = lane & 15, quad = lane >> 4;
    int row0 = blockIdx.y * 64, col0 = blockIdx.x * TN2;

    int r_lo = tid >> 3;                       // 0..31
    int kp = (((tid & 7) ^ (r_lo & 7)) * 8);
    const ushort_t *aSrc[2], *bSrc[2];
    ushort_t *aDst[2], *bDst[2];
    #pragma unroll
    for (int g = 0; g < 2; g++){
        aSrc[g] = A  + (size_t)(row0 + g*32 + r_lo) * K + kp;
        bSrc[g] = BT + (size_t)(col0 + g*32 + r_lo) * K + kp;
        aDst[g] = As + g*2048 + wave*512;
        bDst[g] = Bs + g*2048 + wave*512;
    }

    f32x4 acc[2][2];
    #pragma unroll
    for (int i = 0; i < 2; i++)
        #pragma unroll
        for (int j = 0; j < 2; j++)
            acc[i][j] = (f32x4){0.f, 0.f, 0.f, 0.f};

    for (int kk0 = 0; kk0 < K; kk0 += TK){
        #pragma unroll
        for (int g = 0; g < 2; g++) load_lds16(aSrc[g], aDst[g]);
        #pragma unroll
        for (int g = 0; g < 2; g++) load_lds16(bSrc[g], bDst[g]);
        #pragma unroll
        for (int g = 0; g < 2; g++){ aSrc[g] += TK; bSrc[g] += TK; }
        __syncthreads();

        #pragma unroll
        for (int half = 0; half < 2; half++){
            bf16x8 af[2], bf[2];
            #pragma unroll
            for (int t = 0; t < 2; t++){
                int ra = wm + t*16 + l16;
                int sa = (half*4 + quad) ^ (ra & 7);
                af[t] = *(const bf16x8*)&As[ra * TK + sa * 8];
                int rb = wn + t*16 + l16;
                int sb = (half*4 + quad) ^ (rb & 7);
                bf[t] = *(const bf16x8*)&Bs[rb * TK + sb * 8];
            }
            #pragma unroll
            for (int i = 0; i < 2; i++)
                #pragma unroll
                for (int j = 0; j < 2; j++)
                    acc[i][j] = __builtin_amdgcn_mfma_f32_16x16x32_bf16(af[i], bf[j], acc[i][j], 0, 0, 0);
        }
        __syncthreads();
    }

    // fused bounds epilogue: mix, quad-reduce, one atomicAdd per row per lane-group
    int cc0 = col0 + wn + l16;
    int cc1 = cc0 + 16;
    float pb0 = 0.f, nb0 = 0.f, pb1 = 0.f, nb1 = 0.f;
    if (cc0 < DIN){ pb0 = lu ? u_in[cc0] : l_in[cc0]; nb0 = lu ? l_in[cc0] : u_in[cc0]; }
    if (cc1 < DIN){ pb1 = lu ? u_in[cc1] : l_in[cc1]; nb1 = lu ? l_in[cc1] : u_in[cc1]; }
    #pragma unroll
    for (int i = 0; i < 2; i++){
        int rbase = row0 + wm + i*16 + quad*4;
        #pragma unroll
        for (int rr = 0; rr < 4; rr++){
            int r = rbase + rr;
            float v0 = acc[i][0][rr];
            float s = fmaxf(v0, 0.f) * pb0 + fminf(v0, 0.f) * nb0;
            float v1 = acc[i][1][rr];
            s += fmaxf(v1, 0.f) * pb1 + fminf(v1, 0.f) * nb1;
            s += __shfl_down(s, 8, 16);
            s += __shfl_down(s, 4, 16);
            s += __shfl_down(s, 2, 16);
            s += __shfl_down(s, 1, 16);
            if (l16 == 0) atomicAdd(&accv[r], s);
        }
    }
}

// ---------- fused final-chain GEMV (9 rows), 64-thr blocks, 64 cols x 32-k slices ----------
#define GCOLS 64
#define GKS 32
__global__ __launch_bounds__(64) void gemv9_fused(
    const float* __restrict__ S,
    const float* __restrict__ W4, const float* __restrict__ b4,
    const int* __restrict__ tlp, int mode_w4,
    const float* __restrict__ c_in,
    const float* __restrict__ w_pos, const float* __restrict__ w_neg,
    const float* __restrict__ b_pos, const float* __restrict__ b_neg,
    const float* __restrict__ bias_next,
    const float* __restrict__ B, int K, int N,
    float* __restrict__ C, float* __restrict__ c_out)
{
    __shared__ float Alds[9][GKS];
    int j = threadIdx.x;          // 0..63
    int k0 = blockIdx.y * GKS;
    int tl = mode_w4 ? *tlp : 0;
    float pc[9];
    #pragma unroll
    for (int r = 0; r < 9; r++) pc[r] = 0.f;
    if (j < GKS){
        int k = k0 + j;
        float wp = w_pos[k], wn = w_neg[k], bp = b_pos[k], bn = b_neg[k], bb = bias_next[k];
        #pragma unroll
        for (int r = 0; r < 9; r++){
            float v;
            if (mode_w4){
                int kr = r + (r >= tl ? 1 : 0);
                v = W4[(size_t)kr * K + k] - W4[(size_t)tl * K + k];
            } else {
                v = S[(size_t)r * K + k];
            }
            float p = fmaxf(v, 0.f), n = fminf(v, 0.f);
            float m = p * wp + n * wn;
            Alds[r][j] = m;
            pc[r] = p * bp + n * bn + m * bb;
        }
    }
    if (blockIdx.x == 0){
        #pragma unroll
        for (int r = 0; r < 9; r++){
            float v = pc[r];
            #pragma unroll
            for (int o = 32; o > 0; o >>= 1) v += __shfl_down(v, o, 64);
            if (j == 0){
                if (blockIdx.y == 0)
                    v += mode_w4 ? (b4[r + (r >= tl ? 1 : 0)] - b4[tl]) : c_in[r];
                atomicAdd(&c_out[r], v);
            }
        }
    }
    __syncthreads();
    int col = blockIdx.x * GCOLS + j;
    if (col < N){
        float acc[9] = {0.f,0.f,0.f,0.f,0.f,0.f,0.f,0.f,0.f};
        for (int kk = 0; kk < GKS; kk++){
            float b = B[(size_t)(k0 + kk) * N + col];
            #pragma unroll
            for (int r = 0; r < 9; r++) acc[r] += Alds[r][kk] * b;
        }
        #pragma unroll
        for (int r = 0; r < 9; r++) atomicAdd(&C[(size_t)r * N + col], acc[r]);
    }
}

extern "C" void kernel_launch(void* const* d_in, const int* in_sizes, int n_in,
                              void* d_out, int out_size, void* d_ws, size_t ws_size,
                              hipStream_t stream)
{
    const float* W1  = (const float*)d_in[0];
    const float* b1  = (const float*)d_in[1];
    const float* W2  = (const float*)d_in[2];
    const float* b2  = (const float*)d_in[3];
    const float* W3  = (const float*)d_in[4];
    const float* b3  = (const float*)d_in[5];
    const float* W4  = (const float*)d_in[6];
    const float* b4  = (const float*)d_in[7];
    const float* l_in = (const float*)d_in[8];
    const float* u_in = (const float*)d_in[9];
    const float* p_l1 = (const float*)d_in[10];
    const float* p_u1 = (const float*)d_in[11];
    const float* p_l2 = (const float*)d_in[12];
    const float* p_u2 = (const float*)d_in[13];
    const float* p_l3 = (const float*)d_in[14];
    const float* p_u3 = (const float*)d_in[15];
    const int*   tl   = (const int*)d_in[16];
    float* out = (float*)d_out;

    size_t off = 0;
    auto allocB = [&](size_t bytes) -> void* {
        void* p = (char*)d_ws + off;
        off += (bytes + 255) & ~(size_t)255;
        return p;
    };
    ushort_t* W1bt  = (ushort_t*)allocB((size_t)DPAD * H * 2);
    ushort_t* W2bt  = (ushort_t*)allocB((size_t)H * H * 2);
    ushort_t* Abf_l = (ushort_t*)allocB((size_t)H * H * 2);   // dapply outputs
    ushort_t* Abf_u = (ushort_t*)allocB((size_t)H * H * 2);
    ushort_t* P_l = (ushort_t*)allocB((size_t)H * H * 2);     // NN fused outputs
    ushort_t* P_u = (ushort_t*)allocB((size_t)H * H * 2);
    float *wl1=(float*)allocB(H*4), *wu1=(float*)allocB(H*4), *bl1=(float*)allocB(H*4), *bu1=(float*)allocB(H*4);
    float *wl2=(float*)allocB(H*4), *wu2=(float*)allocB(H*4), *bl2=(float*)allocB(H*4), *bu2=(float*)allocB(H*4);
    float *wl3=(float*)allocB(H*4), *wu3=(float*)allocB(H*4), *bl3=(float*)allocB(H*4), *bu3=(float*)allocB(H*4);
    float *cl_a=(float*)allocB(H*4), *cu_a=(float*)allocB(H*4);
    // ---- zeroed region (one memset): accumulators + final chain ----
    size_t zero_begin = off;
    float *la2=(float*)allocB(H*4), *ua2=(float*)allocB(H*4);
    float *la3=(float*)allocB(H*4), *ua3=(float*)allocB(H*4);
    float *cl_b=(float*)allocB(H*4), *cu_b=(float*)allocB(H*4);
    float* F1  = (float*)allocB(9 * H * 4);
    float* F2  = (float*)allocB(9 * H * 4);
    float* F3  = (float*)allocB(9 * DIN * 4);
    float *c9b=(float*)allocB(64), *c9c=(float*)allocB(64), *c9d=(float*)allocB(64);
    size_t zero_bytes = off - zero_begin;

    dim3 blk(256);
    dim3 gblk(512);
    dim3 gND(DPAD/TN2, H/64, 2);   // 14 x 32 x 2 = 896 blocks

    // 1. zero accumulators (single memset)
    hipMemsetAsync((char*)d_ws + zero_begin, 0, zero_bytes, stream);

    // 2. weight conversion + stage-1 bounds (merged)
    conv_bounds1<<<dim3(H/32, H/32, 3), blk, 0, stream>>>(
        W2, W2bt, W1, W1bt, b1, l_in, u_in, p_l1, p_u1, wl1, wu1, bl1, bu1);

    // 3-5. stage 2: (W2,b2) -> D1 -> [@W1 + fused bounds-mix] -> relax
    dapply_dual<<<H, blk, 0, stream>>>(W2, b2, wl1, wu1, bl1, bu1, b1,
                                       Abf_l, Abf_u, cl_a, cu_a, H);
    gemm_nd_fused<<<gND, blk, 0, stream>>>(Abf_l, Abf_u, W1bt, l_in, u_in,
                                           la2, ua2, H, DPAD, H);
    spu_relax_rows<<<H/256, blk, 0, stream>>>(la2, ua2, cl_a, cu_a, nullptr, nullptr,
                                              p_l2, p_u2, wl2, wu2, bl2, bu2, H);

    // 6-9. stage 3: (W3,b3) -> D2 -> [@W2 + fused D1] -> [@W1 + fused bounds-mix] -> relax
    dapply_dual<<<H, blk, 0, stream>>>(W3, b3, wl2, wu2, bl2, bu2, b2,
                                       Abf_l, Abf_u, cl_a, cu_a, H);
    gemm_nn_fused<<<dim3(H/TN, H/TM, 2), gblk, 0, stream>>>(
        Abf_l, Abf_u, W2bt, P_l, P_u,
        wl1, wu1, bl1, bu1, b1, cl_b, cu_b, H, H, H);
    gemm_nd_fused<<<gND, blk, 0, stream>>>(P_l, P_u, W1bt, l_in, u_in,
                                           la3, ua3, H, DPAD, H);
    spu_relax_rows<<<H/256, blk, 0, stream>>>(la3, ua3, cl_b, cu_b, cl_a, cu_a,
                                              p_l3, p_u3, wl3, wu3, bl3, bu3, H);

    // 10-13. final chain (upper bound only), 9 rows
    gemv9_fused<<<dim3(H/GCOLS, H/GKS), dim3(64), 0, stream>>>(
        nullptr, W4, b4, tl, 1, nullptr,
        wu3, wl3, bu3, bl3, b3, W3, H, H, F1, c9b);
    gemv9_fused<<<dim3(H/GCOLS, H/GKS), dim3(64), 0, stream>>>(
        F1, nullptr, nullptr, nullptr, 0, c9b,
        wu2, wl2, bu2, bl2, b2, W2, H, H, F2, c9c);
    gemv9_fused<<<dim3((DIN + GCOLS - 1)/GCOLS, H/GKS), dim3(64), 0, stream>>>(
        F2, nullptr, nullptr, nullptr, 0, c9c,
        wu1, wl1, bu1, bl1, b1, W1, H, DIN, F3, c9d);
    input_reduce<<<9, blk, 0, stream>>>(F3, c9d, u_in, l_in, out, DIN, DIN);
}

// Round 14
// 306.574 us; speedup vs baseline: 3.8549x; 1.0214x over previous
//
#include <hip/hip_runtime.h>
#include <math.h>

#define H 2048
#define DIN 784
#define DPAD 896   // DIN padded to multiple of 128

typedef unsigned short ushort_t;
typedef __attribute__((ext_vector_type(8))) short bf16x8;
typedef __attribute__((ext_vector_type(4))) float f32x4;
typedef __attribute__((ext_vector_type(4))) unsigned short u16x4;
union F4 { float4 v; float a[4]; };
union U4 { u16x4 v; ushort_t a[4]; };

// ---------- helpers ----------
__device__ __forceinline__ float spu_f(float x){
    if (x >= 0.0f) return x*x - 0.5f;
    float s = 1.0f / (1.0f + __expf(x));   // sigmoid(-x)
    return s - 1.0f;
}
__device__ __forceinline__ float dspu_f(float x){
    if (x >= 0.0f) return 2.0f*x;
    float s = 1.0f / (1.0f + __expf(x));
    return -s * (1.0f - s);
}
__device__ __forceinline__ ushort_t f2bf(float x){
    unsigned u = __float_as_uint(x);
    unsigned r = (u + 0x7FFFu + ((u >> 16) & 1u)) >> 16;
    return (ushort_t)r;
}
__device__ __forceinline__ float bf2f(ushort_t h){
    return __uint_as_float((unsigned)h << 16);
}
__device__ __forceinline__ void load_lds16(const void* g, void* l){
    __builtin_amdgcn_global_load_lds((const __attribute__((address_space(1))) void*)g,
                                     (__attribute__((address_space(3))) void*)l,
                                     16, 0, 0);
}
__device__ __forceinline__ float block_reduce_256(float v, float* red){
    #pragma unroll
    for (int off = 32; off > 0; off >>= 1) v += __shfl_down(v, off, 64);
    int lane = threadIdx.x & 63, w = threadIdx.x >> 6;
    if (lane == 0) red[w] = v;
    __syncthreads();
    float t = 0.f;
    if (threadIdx.x == 0) t = red[0] + red[1] + red[2] + red[3];
    return t;   // valid on thread 0 only
}
__device__ __forceinline__ void block_reduce2_256(float vl, float vu, float* red,
                                                  float& out_l, float& out_u){
    #pragma unroll
    for (int off = 32; off > 0; off >>= 1){
        vl += __shfl_down(vl, off, 64);
        vu += __shfl_down(vu, off, 64);
    }
    int lane = threadIdx.x & 63, w = threadIdx.x >> 6;
    if (lane == 0){ red[w] = vl; red[4 + w] = vu; }
    __syncthreads();
    if (threadIdx.x == 0){
        out_l = red[0] + red[1] + red[2] + red[3];
        out_u = red[4] + red[5] + red[6] + red[7];
    }
}
__device__ __forceinline__ void spu_relax(float l, float u, float pl, float pu,
                                          float& wl_o, float& wu_o, float& bl_o, float& bu_o){
    float k1 = dspu_f(l), k2 = dspu_f(u);
    float klo = fminf(k1, k2), khi = fmaxf(k1, k2);
    float cwl = fminf(fmaxf(pl, klo), khi);
    float cwu = fminf(fmaxf(pu, klo), khi);
    float pts[4];
    pts[0] = l; pts[1] = u; pts[2] = 0.5f*(l+u); pts[3] = fminf(fmaxf(0.f, l), u);
    float bmin = INFINITY, bmax = -INFINITY;
    #pragma unroll
    for (int t = 0; t < 4; t++){
        float sp = spu_f(pts[t]);
        bmin = fminf(bmin, sp - cwl * pts[t]);
        bmax = fmaxf(bmax, sp - cwu * pts[t]);
    }
    wl_o = cwl; wu_o = cwu; bl_o = bmin; bu_o = bmax;
}

// ---------- merged: weight conversion (z=0,1) + stage-1 bounds (z=2) + ws zero (z=3) ----------
__global__ __launch_bounds__(256) void conv_bounds1(
    const float* __restrict__ W2, ushort_t* __restrict__ T2,
    const float* __restrict__ W1, ushort_t* __restrict__ T1,
    const float* __restrict__ b1,
    const float* __restrict__ l_in, const float* __restrict__ u_in,
    const float* __restrict__ pl, const float* __restrict__ pu,
    float* __restrict__ wl, float* __restrict__ wu,
    float* __restrict__ bl, float* __restrict__ bu,
    float* __restrict__ zbase, unsigned zfloats)
{
    int z = blockIdx.z;
    if (z == 3){
        // zero the accumulator region (float4 stores)
        unsigned idx = (blockIdx.y * 64u + blockIdx.x) * 256u + threadIdx.x;
        unsigned q = idx * 4u;
        if (q < zfloats) *(float4*)(zbase + q) = (float4){0.f, 0.f, 0.f, 0.f};
        return;
    }
    if (z < 2){
        __shared__ float tile[32][33];
        const float* W = z ? W1 : W2;
        ushort_t* T = z ? T1 : T2;
        int K = H, N = z ? DIN : H, Npad = z ? DPAD : H;
        if (blockIdx.x * 32 >= (unsigned)Npad) return;
        int n0 = blockIdx.x * 32, k0 = blockIdx.y * 32;
        int tx = threadIdx.x & 31;
        int ty = threadIdx.x >> 5;   // 0..7
        #pragma unroll
        for (int i = 0; i < 32; i += 8){
            int k = k0 + ty + i, n = n0 + tx;
            tile[ty + i][tx] = (k < K && n < N) ? W[(size_t)k * N + n] : 0.f;
        }
        __syncthreads();
        #pragma unroll
        for (int i = 0; i < 32; i += 8){
            int n = n0 + ty + i, k = k0 + tx;
            if (n < Npad && k < K) T[(size_t)n * K + k] = f2bf(tile[tx][ty + i]);
        }
        return;
    }
    // z == 2: stage-1 bounds, row = blockIdx.y*64 + blockIdx.x
    int row = blockIdx.y * 64 + blockIdx.x;
    if (row >= H) return;
    __shared__ float red[8];
    const F4* Mr = (const F4*)(W1 + (size_t)row * DIN);
    const F4* li4 = (const F4*)l_in;
    const F4* ui4 = (const F4*)u_in;
    float accl = 0.f, accu = 0.f;
    for (int q = threadIdx.x; q < DIN/4; q += 256){
        F4 v = Mr[q], lo = li4[q], up = ui4[q];
        #pragma unroll
        for (int c = 0; c < 4; c++){
            float p = fmaxf(v.a[c], 0.f), n = fminf(v.a[c], 0.f);
            accl += p * lo.a[c] + n * up.a[c];
            accu += p * up.a[c] + n * lo.a[c];
        }
    }
    float tl, tu;
    block_reduce2_256(accl, accu, red, tl, tu);
    if (threadIdx.x == 0){
        float bb = b1[row];
        spu_relax(tl + bb, tu + bb, pl[row], pu[row],
                  wl[row], wu[row], bl[row], bu[row]);
    }
}

// ---------- per-row SPU relaxation from fused ND accumulators ----------
__global__ __launch_bounds__(256) void spu_relax_rows(
    const float* __restrict__ accl, const float* __restrict__ accu,
    const float* __restrict__ c1l, const float* __restrict__ c1u,
    const float* __restrict__ c2l, const float* __restrict__ c2u,
    const float* __restrict__ pl, const float* __restrict__ pu,
    float* __restrict__ wl, float* __restrict__ wu,
    float* __restrict__ bl, float* __restrict__ bu, int n)
{
    int i = blockIdx.x * 256 + threadIdx.x;
    if (i >= n) return;
    float l = accl[i] + c1l[i] + (c2l ? c2l[i] : 0.f);
    float u = accu[i] + c1u[i] + (c2u ? c2u[i] : 0.f);
    spu_relax(l, u, pl[i], pu[i], wl[i], wu[i], bl[i], bu[i]);
}

// ---------- dapply: stage-start dual (S shared by l and u, fp32, vectorized) ----------
__global__ __launch_bounds__(256) void dapply_dual(
    const float* __restrict__ S, const float* __restrict__ c_in,
    const float* __restrict__ wl, const float* __restrict__ wu,
    const float* __restrict__ bl, const float* __restrict__ bu,
    const float* __restrict__ bias_next,
    ushort_t* __restrict__ Ml, ushort_t* __restrict__ Mu,
    float* __restrict__ cl_out, float* __restrict__ cu_out, int ncols)
{
    __shared__ float red[8];
    int row = blockIdx.x;
    const F4* S4 = (const F4*)(S + (size_t)row * ncols);
    u16x4* Ml4 = (u16x4*)(Ml + (size_t)row * ncols);
    u16x4* Mu4 = (u16x4*)(Mu + (size_t)row * ncols);
    const F4* wl4 = (const F4*)wl; const F4* wu4 = (const F4*)wu;
    const F4* bl4 = (const F4*)bl; const F4* bu4 = (const F4*)bu;
    const F4* bn4 = (const F4*)bias_next;
    float accl = 0.f, accu = 0.f;
    for (int q = threadIdx.x; q < ncols/4; q += 256){
        F4 v = S4[q], a = wl4[q], b = wu4[q], c = bl4[q], d = bu4[q], e = bn4[q];
        U4 rl, ru;
        #pragma unroll
        for (int k = 0; k < 4; k++){
            float p = fmaxf(v.a[k], 0.f), n = fminf(v.a[k], 0.f);
            float ml = p * a.a[k] + n * b.a[k];
            float mu = p * b.a[k] + n * a.a[k];
            rl.a[k] = f2bf(ml);
            ru.a[k] = f2bf(mu);
            accl += p * c.a[k] + n * d.a[k] + ml * e.a[k];
            accu += p * d.a[k] + n * c.a[k] + mu * e.a[k];
        }
        Ml4[q] = rl.v;
        Mu4[q] = ru.v;
    }
    float tl, tu;
    block_reduce2_256(accl, accu, red, tl, tu);
    if (threadIdx.x == 0){
        float cc = c_in[row];
        cl_out[row] = cc + tl;
        cu_out[row] = cc + tu;
    }
}

// final output: out[row] = c[row] + sum_j mix(M[row][j]; pos_b,neg_b)
__global__ __launch_bounds__(256) void input_reduce(
    const float* __restrict__ M, const float* __restrict__ c,
    const float* __restrict__ pos_b, const float* __restrict__ neg_b,
    float* __restrict__ out, int ncols, int ld)
{
    __shared__ float red[4];
    int row = blockIdx.x;
    const float* Mr = M + (size_t)row * ld;
    float acc = 0.f;
    for (int j = threadIdx.x; j < ncols; j += 256){
        float v = Mr[j];
        acc += fmaxf(v, 0.f) * pos_b[j] + fminf(v, 0.f) * neg_b[j];
    }
    float t = block_reduce_256(acc, red);
    if (threadIdx.x == 0) out[row] = t + c[row];
}

// ---------- NN GEMM pair with FUSED dapply epilogue (full-K), XCD-swizzled ----------
// Grid MUST be (16,16,2). Linear id bits: 0-2 xcd, 3 x-high, 4-7 y, 8 lu.
// Bands x in {xcd, xcd+8} pin to XCD id&7 -> B band (2x512 KB) stays L2-resident.
#define TM 128
#define TN 128
#define TK 64
__global__ __launch_bounds__(512, 4) void gemm_nn_fused(
    const ushort_t* __restrict__ A_l, const ushort_t* __restrict__ A_u,
    const ushort_t* __restrict__ BT,
    ushort_t* __restrict__ O_l, ushort_t* __restrict__ O_u,
    const float* __restrict__ wl1, const float* __restrict__ wu1,
    const float* __restrict__ bl1, const float* __restrict__ bu1,
    const float* __restrict__ b1,
    float* __restrict__ cacc_l, float* __restrict__ cacc_u,
    int M, int N, int K)
{
    __shared__ ushort_t As[TM * TK];
    __shared__ ushort_t Bs[TN * TK];
    int L = blockIdx.x + (blockIdx.y << 4) + (blockIdx.z << 8);
    int bx = (L & 7) + (((L >> 3) & 1) << 3);   // 0..15
    int by = (L >> 4) & 15;                     // 0..15
    int lu = L >> 8;                            // 0..1
    const ushort_t* A = lu ? A_u : A_l;
    ushort_t* O = lu ? O_u : O_l;
    float* cacc = lu ? cacc_u : cacc_l;
    const float* wp_a = lu ? wu1 : wl1;
    const float* wn_a = lu ? wl1 : wu1;
    const float* bp_a = lu ? bu1 : bl1;
    const float* bn_a = lu ? bl1 : bu1;

    int tid  = threadIdx.x;
    int wave = tid >> 6, lane = tid & 63;
    int wm = (wave >> 2) * 64, wn = (wave & 3) * 32;
    int l16 = lane & 15, quad = lane >> 4;
    int row0 = by * TM, col0 = bx * TN;

    int r_lo = tid >> 3;
    int kp = (((tid & 7) ^ (r_lo & 7)) * 8);
    const ushort_t *aSrc[2], *bSrc[2];
    ushort_t *aDst[2], *bDst[2];
    #pragma unroll
    for (int g = 0; g < 2; g++){
        aSrc[g] = A  + (size_t)(row0 + g*64 + r_lo) * K + kp;
        bSrc[g] = BT + (size_t)(col0 + g*64 + r_lo) * K + kp;
        aDst[g] = As + g*4096 + wave*512;
        bDst[g] = Bs + g*4096 + wave*512;
    }

    f32x4 acc[4][2];
    #pragma unroll
    for (int i = 0; i < 4; i++)
        #pragma unroll
        for (int j = 0; j < 2; j++)
            acc[i][j] = (f32x4){0.f, 0.f, 0.f, 0.f};

    for (int kk0 = 0; kk0 < K; kk0 += TK){
        #pragma unroll
        for (int g = 0; g < 2; g++) load_lds16(aSrc[g], aDst[g]);
        #pragma unroll
        for (int g = 0; g < 2; g++) load_lds16(bSrc[g], bDst[g]);
        #pragma unroll
        for (int g = 0; g < 2; g++){ aSrc[g] += TK; bSrc[g] += TK; }
        __syncthreads();

        #pragma unroll
        for (int half = 0; half < 2; half++){
            bf16x8 af[4], bf[2];
            #pragma unroll
            for (int t = 0; t < 4; t++){
                int ra = wm + t*16 + l16;
                int sa = (half*4 + quad) ^ (ra & 7);
                af[t] = *(const bf16x8*)&As[ra * TK + sa * 8];
            }
            #pragma unroll
            for (int t = 0; t < 2; t++){
                int rb = wn + t*16 + l16;
                int sb = (half*4 + quad) ^ (rb & 7);
                bf[t] = *(const bf16x8*)&Bs[rb * TK + sb * 8];
            }
            #pragma unroll
            for (int i = 0; i < 4; i++)
                #pragma unroll
                for (int j = 0; j < 2; j++)
                    acc[i][j] = __builtin_amdgcn_mfma_f32_16x16x32_bf16(af[i], bf[j], acc[i][j], 0, 0, 0);
        }
        __syncthreads();
    }

    // fused dapply epilogue (C/D layout: col = lane&15, row = quad*4 + reg)
    int cc0 = col0 + wn + l16;
    int cc1 = cc0 + 16;
    float wp0 = wp_a[cc0], wn0 = wn_a[cc0], bp0 = bp_a[cc0], bn0 = bn_a[cc0], bb0 = b1[cc0];
    float wp1 = wp_a[cc1], wn1 = wn_a[cc1], bp1 = bp_a[cc1], bn1 = bn_a[cc1], bb1 = b1[cc1];
    #pragma unroll
    for (int i = 0; i < 4; i++){
        int rbase = row0 + wm + i*16 + quad*4;
        #pragma unroll
        for (int rr = 0; rr < 4; rr++){
            int r = rbase + rr;
            float v0 = acc[i][0][rr];
            float p0 = fmaxf(v0, 0.f), n0 = fminf(v0, 0.f);
            float m0 = p0 * wp0 + n0 * wn0;
            O[(size_t)r * N + cc0] = f2bf(m0);
            float s = p0 * bp0 + n0 * bn0 + m0 * bb0;
            float v1 = acc[i][1][rr];
            float p1 = fmaxf(v1, 0.f), n1 = fminf(v1, 0.f);
            float m1 = p1 * wp1 + n1 * wn1;
            O[(size_t)r * N + cc1] = f2bf(m1);
            s += p1 * bp1 + n1 * bn1 + m1 * bb1;
            s += __shfl_down(s, 8, 16);
            s += __shfl_down(s, 4, 16);
            s += __shfl_down(s, 2, 16);
            s += __shfl_down(s, 1, 16);
            if (l16 == 0) atomicAdd(&cacc[r], s);
        }
    }
}

// ---------- ND GEMM pair, 64x64 tile, fused bounds-mix epilogue (plain atomics) ----------
#define TN2 64
__global__ __launch_bounds__(256, 4) void gemm_nd_fused(
    const ushort_t* __restrict__ A_l, const ushort_t* __restrict__ A_u,
    const ushort_t* __restrict__ BT,
    const float* __restrict__ l_in, const float* __restrict__ u_in,
    float* __restrict__ acc_l, float* __restrict__ acc_u,
    int M, int N, int K)
{
    __shared__ ushort_t As[64 * TK];   // 8 KB
    __shared__ ushort_t Bs[64 * TK];   // 8 KB
    int lu = blockIdx.z;
    const ushort_t* A = lu ? A_u : A_l;
    float* accv = lu ? acc_u : acc_l;

    int tid  = threadIdx.x;
    int wave = tid >> 6, lane = tid & 63;
    int wm = (wave >> 1) * 32, wn = (wave & 1) * 32;
    int l16 = lane & 15, quad = lane >> 4;
    int row0 = blockIdx.y * 64, col0 = blockIdx.x * TN2;

    int r_lo = tid >> 3;                       // 0..31
    int kp = (((tid & 7) ^ (r_lo & 7)) * 8);
    const ushort_t *aSrc[2], *bSrc[2];
    ushort_t *aDst[2], *bDst[2];
    #pragma unroll
    for (int g = 0; g < 2; g++){
        aSrc[g] = A  + (size_t)(row0 + g*32 + r_lo) * K + kp;
        bSrc[g] = BT + (size_t)(col0 + g*32 + r_lo) * K + kp;
        aDst[g] = As + g*2048 + wave*512;
        bDst[g] = Bs + g*2048 + wave*512;
    }

    f32x4 acc[2][2];
    #pragma unroll
    for (int i = 0; i < 2; i++)
        #pragma unroll
        for (int j = 0; j < 2; j++)
            acc[i][j] = (f32x4){0.f, 0.f, 0.f, 0.f};

    for (int kk0 = 0; kk0 < K; kk0 += TK){
        #pragma unroll
        for (int g = 0; g < 2; g++) load_lds16(aSrc[g], aDst[g]);
        #pragma unroll
        for (int g = 0; g < 2; g++) load_lds16(bSrc[g], bDst[g]);
        #pragma unroll
        for (int g = 0; g < 2; g++){ aSrc[g] += TK; bSrc[g] += TK; }
        __syncthreads();

        #pragma unroll
        for (int half = 0; half < 2; half++){
            bf16x8 af[2], bf[2];
            #pragma unroll
            for (int t = 0; t < 2; t++){
                int ra = wm + t*16 + l16;
                int sa = (half*4 + quad) ^ (ra & 7);
                af[t] = *(const bf16x8*)&As[ra * TK + sa * 8];
                int rb = wn + t*16 + l16;
                int sb = (half*4 + quad) ^ (rb & 7);
                bf[t] = *(const bf16x8*)&Bs[rb * TK + sb * 8];
            }
            #pragma unroll
            for (int i = 0; i < 2; i++)
                #pragma unroll
                for (int j = 0; j < 2; j++)
                    acc[i][j] = __builtin_amdgcn_mfma_f32_16x16x32_bf16(af[i], bf[j], acc[i][j], 0, 0, 0);
        }
        __syncthreads();
    }

    // fused bounds epilogue: mix, quad-reduce, one atomicAdd per row per lane-group
    int cc0 = col0 + wn + l16;
    int cc1 = cc0 + 16;
    float pb0 = 0.f, nb0 = 0.f, pb1 = 0.f, nb1 = 0.f;
    if (cc0 < DIN){ pb0 = lu ? u_in[cc0] : l_in[cc0]; nb0 = lu ? l_in[cc0] : u_in[cc0]; }
    if (cc1 < DIN){ pb1 = lu ? u_in[cc1] : l_in[cc1]; nb1 = lu ? l_in[cc1] : u_in[cc1]; }
    #pragma unroll
    for (int i = 0; i < 2; i++){
        int rbase = row0 + wm + i*16 + quad*4;
        #pragma unroll
        for (int rr = 0; rr < 4; rr++){
            int r = rbase + rr;
            float v0 = acc[i][0][rr];
            float s = fmaxf(v0, 0.f) * pb0 + fminf(v0, 0.f) * nb0;
            float v1 = acc[i][1][rr];
            s += fmaxf(v1, 0.f) * pb1 + fminf(v1, 0.f) * nb1;
            s += __shfl_down(s, 8, 16);
            s += __shfl_down(s, 4, 16);
            s += __shfl_down(s, 2, 16);
            s += __shfl_down(s, 1, 16);
            if (l16 == 0) atomicAdd(&accv[r], s);
        }
    }
}

// ---------- fused final-chain GEMV (9 rows), 64-thr blocks, 64 cols x 32-k slices ----------
#define GCOLS 64
#define GKS 32
__global__ __launch_bounds__(64) void gemv9_fused(
    const float* __restrict__ S,
    const float* __restrict__ W4, const float* __restrict__ b4,
    const int* __restrict__ tlp, int mode_w4,
    const float* __restrict__ c_in,
    const float* __restrict__ w_pos, const float* __restrict__ w_neg,
    const float* __restrict__ b_pos, const float* __restrict__ b_neg,
    const float* __restrict__ bias_next,
    const float* __restrict__ B, int K, int N,
    float* __restrict__ C, float* __restrict__ c_out)
{
    __shared__ float Alds[9][GKS];
    int j = threadIdx.x;          // 0..63
    int k0 = blockIdx.y * GKS;
    int tl = mode_w4 ? *tlp : 0;
    float pc[9];
    #pragma unroll
    for (int r = 0; r < 9; r++) pc[r] = 0.f;
    if (j < GKS){
        int k = k0 + j;
        float wp = w_pos[k], wn = w_neg[k], bp = b_pos[k], bn = b_neg[k], bb = bias_next[k];
        #pragma unroll
        for (int r = 0; r < 9; r++){
            float v;
            if (mode_w4){
                int kr = r + (r >= tl ? 1 : 0);
                v = W4[(size_t)kr * K + k] - W4[(size_t)tl * K + k];
            } else {
                v = S[(size_t)r * K + k];
            }
            float p = fmaxf(v, 0.f), n = fminf(v, 0.f);
            float m = p * wp + n * wn;
            Alds[r][j] = m;
            pc[r] = p * bp + n * bn + m * bb;
        }
    }
    if (blockIdx.x == 0){
        #pragma unroll
        for (int r = 0; r < 9; r++){
            float v = pc[r];
            #pragma unroll
            for (int o = 32; o > 0; o >>= 1) v += __shfl_down(v, o, 64);
            if (j == 0){
                if (blockIdx.y == 0)
                    v += mode_w4 ? (b4[r + (r >= tl ? 1 : 0)] - b4[tl]) : c_in[r];
                atomicAdd(&c_out[r], v);
            }
        }
    }
    __syncthreads();
    int col = blockIdx.x * GCOLS + j;
    if (col < N){
        float acc[9] = {0.f,0.f,0.f,0.f,0.f,0.f,0.f,0.f,0.f};
        for (int kk = 0; kk < GKS; kk++){
            float b = B[(size_t)(k0 + kk) * N + col];
            #pragma unroll
            for (int r = 0; r < 9; r++) acc[r] += Alds[r][kk] * b;
        }
        #pragma unroll
        for (int r = 0; r < 9; r++) atomicAdd(&C[(size_t)r * N + col], acc[r]);
    }
}

extern "C" void kernel_launch(void* const* d_in, const int* in_sizes, int n_in,
                              void* d_out, int out_size, void* d_ws, size_t ws_size,
                              hipStream_t stream)
{
    const float* W1  = (const float*)d_in[0];
    const float* b1  = (const float*)d_in[1];
    const float* W2  = (const float*)d_in[2];
    const float* b2  = (const float*)d_in[3];
    const float* W3  = (const float*)d_in[4];
    const float* b3  = (const float*)d_in[5];
    const float* W4  = (const float*)d_in[6];
    const float* b4  = (const float*)d_in[7];
    const float* l_in = (const float*)d_in[8];
    const float* u_in = (const float*)d_in[9];
    const float* p_l1 = (const float*)d_in[10];
    const float* p_u1 = (const float*)d_in[11];
    const float* p_l2 = (const float*)d_in[12];
    const float* p_u2 = (const float*)d_in[13];
    const float* p_l3 = (const float*)d_in[14];
    const float* p_u3 = (const float*)d_in[15];
    const int*   tl   = (const int*)d_in[16];
    float* out = (float*)d_out;

    size_t off = 0;
    auto allocB = [&](size_t bytes) -> void* {
        void* p = (char*)d_ws + off;
        off += (bytes + 255) & ~(size_t)255;
        return p;
    };
    ushort_t* W1bt  = (ushort_t*)allocB((size_t)DPAD * H * 2);
    ushort_t* W2bt  = (ushort_t*)allocB((size_t)H * H * 2);
    ushort_t* Abf_l = (ushort_t*)allocB((size_t)H * H * 2);   // dapply outputs
    ushort_t* Abf_u = (ushort_t*)allocB((size_t)H * H * 2);
    ushort_t* P_l = (ushort_t*)allocB((size_t)H * H * 2);     // NN fused outputs
    ushort_t* P_u = (ushort_t*)allocB((size_t)H * H * 2);
    float *wl1=(float*)allocB(H*4), *wu1=(float*)allocB(H*4), *bl1=(float*)allocB(H*4), *bu1=(float*)allocB(H*4);
    float *wl2=(float*)allocB(H*4), *wu2=(float*)allocB(H*4), *bl2=(float*)allocB(H*4), *bu2=(float*)allocB(H*4);
    float *wl3=(float*)allocB(H*4), *wu3=(float*)allocB(H*4), *bl3=(float*)allocB(H*4), *bu3=(float*)allocB(H*4);
    float *cl_a=(float*)allocB(H*4), *cu_a=(float*)allocB(H*4);
    // ---- zeroed region (by conv_bounds1 z=3): accumulators + final chain ----
    size_t zero_begin = off;
    float *la2=(float*)allocB(H*4), *ua2=(float*)allocB(H*4);
    float *la3=(float*)allocB(H*4), *ua3=(float*)allocB(H*4);
    float *cl_b=(float*)allocB(H*4), *cu_b=(float*)allocB(H*4);
    float* F1  = (float*)allocB(9 * H * 4);
    float* F2  = (float*)allocB(9 * H * 4);
    float* F3  = (float*)allocB(9 * DIN * 4);
    float *c9b=(float*)allocB(64), *c9c=(float*)allocB(64), *c9d=(float*)allocB(64);
    size_t zero_bytes = off - zero_begin;
    float* zbase = (float*)((char*)d_ws + zero_begin);
    unsigned zfloats = (unsigned)(zero_bytes / 4);

    dim3 blk(256);
    dim3 gblk(512);
    dim3 gND(DPAD/TN2, H/64, 2);   // 14 x 32 x 2 = 896 blocks

    // 1. weight conversion + stage-1 bounds + zero accumulators (single dispatch)
    conv_bounds1<<<dim3(H/32, H/32, 4), blk, 0, stream>>>(
        W2, W2bt, W1, W1bt, b1, l_in, u_in, p_l1, p_u1, wl1, wu1, bl1, bu1,
        zbase, zfloats);

    // 2-4. stage 2: (W2,b2) -> D1 -> [@W1 + fused bounds-mix] -> relax
    dapply_dual<<<H, blk, 0, stream>>>(W2, b2, wl1, wu1, bl1, bu1, b1,
                                       Abf_l, Abf_u, cl_a, cu_a, H);
    gemm_nd_fused<<<gND, blk, 0, stream>>>(Abf_l, Abf_u, W1bt, l_in, u_in,
                                           la2, ua2, H, DPAD, H);
    spu_relax_rows<<<H/256, blk, 0, stream>>>(la2, ua2, cl_a, cu_a, nullptr, nullptr,
                                              p_l2, p_u2, wl2, wu2, bl2, bu2, H);

    // 5-8. stage 3: (W3,b3) -> D2 -> [@W2 + fused D1] -> [@W1 + fused bounds-mix] -> relax
    dapply_dual<<<H, blk, 0, stream>>>(W3, b3, wl2, wu2, bl2, bu2, b2,
                                       Abf_l, Abf_u, cl_a, cu_a, H);
    gemm_nn_fused<<<dim3(H/TN, H/TM, 2), gblk, 0, stream>>>(
        Abf_l, Abf_u, W2bt, P_l, P_u,
        wl1, wu1, bl1, bu1, b1, cl_b, cu_b, H, H, H);
    gemm_nd_fused<<<gND, blk, 0, stream>>>(P_l, P_u, W1bt, l_in, u_in,
                                           la3, ua3, H, DPAD, H);
    spu_relax_rows<<<H/256, blk, 0, stream>>>(la3, ua3, cl_b, cu_b, cl_a, cu_a,
                                              p_l3, p_u3, wl3, wu3, bl3, bu3, H);

    // 9-12. final chain (upper bound only), 9 rows
    gemv9_fused<<<dim3(H/GCOLS, H/GKS), dim3(64), 0, stream>>>(
        nullptr, W4, b4, tl, 1, nullptr,
        wu3, wl3, bu3, bl3, b3, W3, H, H, F1, c9b);
    gemv9_fused<<<dim3(H/GCOLS, H/GKS), dim3(64), 0, stream>>>(
        F1, nullptr, nullptr, nullptr, 0, c9b,
        wu2, wl2, bu2, bl2, b2, W2, H, H, F2, c9c);
    gemv9_fused<<<dim3((DIN + GCOLS - 1)/GCOLS, H/GKS), dim3(64), 0, stream>>>(
        F2, nullptr, nullptr, nullptr, 0, c9c,
        wu1, wl1, bu1, bl1, b1, W1, H, DIN, F3, c9d);
    input_reduce<<<9, blk, 0, stream>>>(F3, c9d, u_in, l_in, out, DIN, DIN);
}